// Round 1
// baseline (316.674 us; speedup 1.0000x reference)
//
#include <hip/hip_runtime.h>
#include <hip/hip_bf16.h>
#include <stdint.h>

typedef short    s16x8  __attribute__((ext_vector_type(8)));
typedef __bf16   bf16x8 __attribute__((ext_vector_type(8)));
typedef float    f32x4  __attribute__((ext_vector_type(4)));

__device__ __forceinline__ unsigned short f2bf(float f) {
    union { float f; unsigned u; } v; v.f = f;
    unsigned r = v.u + 0x7FFFu + ((v.u >> 16) & 1u);
    return (unsigned short)(r >> 16);
}
__device__ __forceinline__ float bf2f(unsigned short s) {
    union { unsigned u; float f; } v; v.u = ((unsigned)s) << 16;
    return v.f;
}

__device__ __forceinline__ void gload16(const void* g, void* l) {
    __builtin_amdgcn_global_load_lds(
        (const __attribute__((address_space(1))) void*)(uintptr_t)g,
        (__attribute__((address_space(3))) void*)(uintptr_t)l,
        16, 0, 0);
}

// ---------------- fp32 -> bf16 conversion (vectorized, grid-stride) ----------
__global__ __launch_bounds__(256) void cvt_bf16(const float* __restrict__ in,
                                                unsigned short* __restrict__ out,
                                                int n4) {
    int i = blockIdx.x * blockDim.x + threadIdx.x;
    int stride = gridDim.x * blockDim.x;
    for (; i < n4; i += stride) {
        const float4 v = *(const float4*)(in + (size_t)i * 4);
        ushort4 o;
        o.x = f2bf(v.x); o.y = f2bf(v.y); o.z = f2bf(v.z); o.w = f2bf(v.w);
        *(ushort4*)(out + (size_t)i * 4) = o;
    }
}

// ---------------- bf16 GEMM:  C[M][N] = A[M][K] @ B[N][K]^T + bias ----------
// 128x128 tile, BK=32, 4 waves (2x2 of 64x64), 16x16x32 bf16 MFMA.
template<bool OUT_BF16>
__global__ __launch_bounds__(256) void gemm_bt(
        const unsigned short* __restrict__ A,   // [M][K] bf16
        const unsigned short* __restrict__ B,   // [N][K] bf16
        const float* __restrict__ bias,         // [N] fp32
        void* __restrict__ Cvoid,               // [M][N] bf16 or fp32
        int M, int N, int K) {
    constexpr int BM = 128, BN = 128, BK = 32;
    __shared__ unsigned short As[BM * BK];
    __shared__ unsigned short Bs[BN * BK];
    const int tid  = threadIdx.x;
    const int lane = tid & 63;
    const int wv   = tid >> 6;
    const int ntn  = N / BN;
    const int bm   = (int)blockIdx.x / ntn;
    const int bn   = (int)blockIdx.x % ntn;
    const int wr   = (wv >> 1) * 64;     // wave row offset in tile
    const int wc   = (wv & 1) * 64;      // wave col offset in tile
    const int lr   = lane & 15;
    const int lk   = (lane >> 4) * 8;

    f32x4 acc[4][4] = {};

    for (int k0 = 0; k0 < K; k0 += BK) {
        // stage A and B tiles: 128*32*2B = 8192 B each; 2 passes of 256thr*16B
        #pragma unroll
        for (int i = 0; i < 2; ++i) {
            int f   = i * 4096 + tid * 16;   // byte offset into LDS tile
            int row = f >> 6;                // / (BK*2 bytes per row)
            int col = (f & 63) >> 1;         // short index within row
            gload16(A + (size_t)(bm * BM + row) * K + k0 + col, (char*)As + f);
            gload16(B + (size_t)(bn * BN + row) * K + k0 + col, (char*)Bs + f);
        }
        __syncthreads();

        bf16x8 af[4], bfr[4];
        #pragma unroll
        for (int m = 0; m < 4; ++m)
            af[m] = *(const bf16x8*)(As + (wr + m * 16 + lr) * BK + lk);
        #pragma unroll
        for (int n = 0; n < 4; ++n)
            bfr[n] = *(const bf16x8*)(Bs + (wc + n * 16 + lr) * BK + lk);
        #pragma unroll
        for (int m = 0; m < 4; ++m)
            #pragma unroll
            for (int n = 0; n < 4; ++n)
                acc[m][n] = __builtin_amdgcn_mfma_f32_16x16x32_bf16(
                    af[m], bfr[n], acc[m][n], 0, 0, 0);
        __syncthreads();
    }

    // epilogue: C[row][col] with col=lane&15, row=(lane>>4)*4+j (verified layout)
    const int r0 = bm * BM + wr + (lane >> 4) * 4;
    const int c0 = bn * BN + wc + lr;
    #pragma unroll
    for (int n = 0; n < 4; ++n) {
        const int gc = c0 + n * 16;
        const float bv = bias[gc];
        #pragma unroll
        for (int m = 0; m < 4; ++m) {
            #pragma unroll
            for (int j = 0; j < 4; ++j) {
                const int gr = r0 + m * 16 + j;
                const float v = acc[m][n][j] + bv;
                if constexpr (OUT_BF16)
                    ((unsigned short*)Cvoid)[(size_t)gr * N + gc] = f2bf(v);
                else
                    ((float*)Cvoid)[(size_t)gr * N + gc] = v;
            }
        }
    }
}

// ---------------- per-token attention over heads (8x8 softmax) --------------
// One wave per token. lane = h*8 + c; lane owns head h, dims [c*8, c*8+8).
__global__ __launch_bounds__(256) void attn_heads(
        const unsigned short* __restrict__ qkv,   // [M][1536] bf16
        unsigned short* __restrict__ val,         // [M][512]  bf16
        int M) {
    const int t    = blockIdx.x * 4 + (threadIdx.x >> 6);
    const int lane = threadIdx.x & 63;
    const int h    = lane >> 3;
    const int c    = lane & 7;
    const unsigned short* base = qkv + (size_t)t * 1536;

    s16x8 q8 = *(const s16x8*)(base + h * 192 + c * 8);
    float qf[8];
    #pragma unroll
    for (int j = 0; j < 8; ++j) qf[j] = bf2f((unsigned short)q8[j]);

    float s[8];
    #pragma unroll
    for (int g = 0; g < 8; ++g) {
        s16x8 k8 = *(const s16x8*)(base + g * 192 + 64 + c * 8);
        float p = 0.f;
        #pragma unroll
        for (int j = 0; j < 8; ++j) p += qf[j] * bf2f((unsigned short)k8[j]);
        s[g] = p;
    }
    // reduce partial dots across the 8 lanes of this head group (xor 1,2,4)
    #pragma unroll
    for (int mask = 1; mask <= 4; mask <<= 1)
        #pragma unroll
        for (int g = 0; g < 8; ++g)
            s[g] += __shfl_xor(s[g], mask, 64);

    // scale + softmax over g (each lane has the full row)
    float mx = -1e30f;
    #pragma unroll
    for (int g = 0; g < 8; ++g) { s[g] *= 0.125f; mx = fmaxf(mx, s[g]); }
    float sum = 0.f;
    #pragma unroll
    for (int g = 0; g < 8; ++g) { s[g] = __expf(s[g] - mx); sum += s[g]; }
    const float inv = 1.f / sum;

    float acc[8] = {0.f,0.f,0.f,0.f,0.f,0.f,0.f,0.f};
    #pragma unroll
    for (int g = 0; g < 8; ++g) {
        s16x8 v8 = *(const s16x8*)(base + g * 192 + 128 + c * 8);
        const float ag = s[g] * inv;
        #pragma unroll
        for (int j = 0; j < 8; ++j) acc[j] += ag * bf2f((unsigned short)v8[j]);
    }
    s16x8 ov;
    #pragma unroll
    for (int j = 0; j < 8; ++j) ov[j] = (short)f2bf(acc[j]);
    *(s16x8*)(val + (size_t)t * 512 + h * 64 + c * 8) = ov;
}

// ---------------------------------------------------------------------------
extern "C" void kernel_launch(void* const* d_in, const int* in_sizes, int n_in,
                              void* d_out, int out_size, void* d_ws, size_t ws_size,
                              hipStream_t stream) {
    const float* x     = (const float*)d_in[0];
    const float* w_qkv = (const float*)d_in[1];
    const float* b_qkv = (const float*)d_in[2];
    const float* w_out = (const float*)d_in[3];
    const float* b_out = (const float*)d_in[4];
    float* out = (float*)d_out;

    const int DM = 512;
    const int M  = in_sizes[0] / DM;      // 61440 tokens

    unsigned short* xb    = (unsigned short*)d_ws;          // M*512
    unsigned short* wqkvb = xb + (size_t)M * DM;            // 1536*512
    unsigned short* woutb = wqkvb + (size_t)3 * DM * DM;    // 512*512
    unsigned short* qkvb  = woutb + (size_t)DM * DM;        // M*1536
    unsigned short* valb  = xb;   // reuse x_bf16 buffer after GEMM1 consumed it

    cvt_bf16<<<2048, 256, 0, stream>>>(x, xb, M * DM / 4);
    cvt_bf16<<<96,   256, 0, stream>>>(w_qkv, wqkvb, 3 * DM * DM / 4);
    cvt_bf16<<<32,   256, 0, stream>>>(w_out, woutb, DM * DM / 4);

    // GEMM1: qkv[M][1536] = x @ w_qkv^T + b_qkv (bf16 out)
    gemm_bt<true><<<dim3((M / 128) * (3 * DM / 128)), 256, 0, stream>>>(
        xb, wqkvb, b_qkv, qkvb, M, 3 * DM, DM);

    // per-token attention over heads
    attn_heads<<<M / 4, 256, 0, stream>>>(qkvb, valb, M);

    // GEMM2: out[M][512] = val @ w_out^T + b_out (fp32 out)
    gemm_bt<false><<<dim3((M / 128) * (DM / 128)), 256, 0, stream>>>(
        valb, woutb, b_out, out, M, DM, DM);
}